// Round 1
// baseline (120.569 us; speedup 1.0000x reference)
//
#include <hip/hip_runtime.h>
#include <math.h>

// YOLO loss, 3 scales: G in {13,26,52}, B=32, A=3, 85 ch (5+80), IMG=416.
// Inputs (setup_inputs dict order): fm0, yt0, fm1, yt1, fm2, yt2, anchors(9x2)
// Output: 5 floats: total, xy, wh, conf, prob

constexpr int   NCLS  = 80;
constexpr int   KMAX  = 32;
constexpr float IMGF  = 416.0f;

// cells per scale: 32 * 3 * G*G
constexpr int C0 = 32 * 3 * 169;    // 16224
constexpr int C1 = 32 * 3 * 676;    // 64896
constexpr int C2 = 32 * 3 * 2704;   // 259584
constexpr int TOTAL_CELLS = C0 + C1 + C2; // 340704

// ws layout:
//   [0,32)        double acc[4]  : xy, wh, conf, prob   (raw sums)
//   [32,416)      int cnt[96]    : per (scale*32+b) target count
//   [416,49568)   float tgt[96][32][4] : x,y,w,h
//   [49568,61856) int tgtn[96][32]     : flattened cell index n
//   [61856,...)   float objc[TOTAL_CELLS] : obj mask, layout [s][b][a][sp]
constexpr size_t OFF_CNT  = 32;
constexpr size_t OFF_TGT  = 416;
constexpr size_t OFF_TGTN = OFF_TGT + 96 * KMAX * 4 * sizeof(float);   // 49568
constexpr size_t OFF_OBJC = OFF_TGTN + 96 * KMAX * sizeof(int);        // 61856

__global__ __launch_bounds__(128) void k_init(double* acc, int* cnt) {
    int t = threadIdx.x;
    if (t < 4)  acc[t] = 0.0;
    if (t < 96) cnt[t] = 0;
}

__global__ __launch_bounds__(256) void k_collect(
        const float* __restrict__ yt0, const float* __restrict__ yt1,
        const float* __restrict__ yt2,
        int* __restrict__ cnt, float* __restrict__ tgt, int* __restrict__ tgtn,
        float* __restrict__ objc) {
    int t = blockIdx.x * 256 + threadIdx.x;
    if (t >= TOTAL_CELLS) return;
    int s, local, G;
    const float* yt;
    if (t < C0)           { s = 0; local = t;          G = 13; yt = yt0; }
    else if (t < C0 + C1) { s = 1; local = t - C0;     G = 26; yt = yt1; }
    else                  { s = 2; local = t - C0 - C1; G = 52; yt = yt2; }
    int GG = G * G;
    int b  = local / (3 * GG);
    int r  = local - b * 3 * GG;
    int a  = r / GG;
    int sp = r - a * GG;
    int n  = sp * 3 + a;                 // reference's flattened N index
    int yidx = (b * 3 * GG + n) * 85;
    float obj = yt[yidx + 4];
    if (objc) objc[t] = obj;             // layout [s][b][a][sp]: coalesced read in k_conf
    if (obj > 0.5f) {
        int pos = atomicAdd(&cnt[s * 32 + b], 1);
        if (pos < KMAX) {
            float4 box = make_float4(yt[yidx], yt[yidx + 1], yt[yidx + 2], yt[yidx + 3]);
            reinterpret_cast<float4*>(tgt)[(s * 32 + b) * KMAX + pos] = box;
            tgtn[(s * 32 + b) * KMAX + pos] = n;
        }
    }
}

__device__ inline float sigmoidf_(float x) { return 1.0f / (1.0f + expf(-x)); }
__device__ inline float bcef_(float l, float t) {
    return fmaxf(l, 0.0f) - l * t + log1pf(expf(-fabsf(l)));
}

// conf loss over all cells. grid: 96 + 288 + 1056 = 1440 blocks of 256.
__global__ __launch_bounds__(256) void k_conf(
        const float* __restrict__ fm0, const float* __restrict__ fm1,
        const float* __restrict__ fm2,
        const float* __restrict__ yt0, const float* __restrict__ yt1,
        const float* __restrict__ yt2,
        const float* __restrict__ anch,
        const int* __restrict__ cnt, const float* __restrict__ tgt,
        const float* __restrict__ objc, double* __restrict__ acc) {
    int blk = blockIdx.x;
    const float *fm, *yt;
    int G, chunks, s, anchoff, objbase;
    if (blk < 96)       { fm = fm0; yt = yt0; G = 13; chunks = 1;  s = 0; anchoff = 6; objbase = 0; }
    else if (blk < 384) { blk -= 96;  fm = fm1; yt = yt1; G = 26; chunks = 3;  s = 1; anchoff = 3; objbase = C0; }
    else                { blk -= 384; fm = fm2; yt = yt2; G = 52; chunks = 11; s = 2; anchoff = 0; objbase = C0 + C1; }
    int chunk = blk % chunks;
    int ba    = blk / chunks;     // b*3 + a
    int b = ba / 3, a = ba % 3;
    int GG = G * G;
    float stridef = IMGF / (float)G;   // 32/16/8, exact powers of 2

    __shared__ float4 s_tgt[KMAX];
    __shared__ int    s_cnt;
    if (threadIdx.x == 0) s_cnt = cnt[s * 32 + b];
    if (threadIdx.x < KMAX)
        s_tgt[threadIdx.x] = reinterpret_cast<const float4*>(tgt)[(s * 32 + b) * KMAX + threadIdx.x];
    __syncthreads();

    int sp = chunk * 256 + threadIdx.x;
    float local = 0.0f;
    if (sp < GG) {
        int jj = sp % G, ii = sp / G;
        int fbase = (b * 255 + a * 85) * GG + sp;
        float p0 = fm[fbase];
        float p1 = fm[fbase + GG];
        float p2 = fm[fbase + 2 * GG];
        float p3 = fm[fbase + 3 * GG];
        float p4 = fm[fbase + 4 * GG];
        float m;
        if (objc) m = objc[objbase + (b * 3 + a) * GG + sp];
        else      m = yt[(b * 3 * GG + sp * 3 + a) * 85 + 4];
        float aw = anch[(anchoff + a) * 2], ah = anch[(anchoff + a) * 2 + 1];
        // predicted box (replicates reference arithmetic)
        float cx = (sigmoidf_(p0) + (float)jj) * stridef;
        float cy = (sigmoidf_(p1) + (float)ii) * stridef;
        float pw = expf(p2) * (aw / stridef) * stridef;
        float ph = expf(p3) * (ah / stridef) * stridef;
        float parea = pw * ph;
        int cn = s_cnt;
        float best = 0.0f;
        for (int k = 0; k < cn; ++k) {
            float4 tb = s_tgt[k];
            float minx = fmaxf(cx - pw * 0.5f, tb.x - tb.z * 0.5f);
            float maxx = fminf(cx + pw * 0.5f, tb.x + tb.z * 0.5f);
            float miny = fmaxf(cy - ph * 0.5f, tb.y - tb.w * 0.5f);
            float maxy = fminf(cy + ph * 0.5f, tb.y + tb.w * 0.5f);
            float iw = fmaxf(maxx - minx, 0.0f);
            float ih = fmaxf(maxy - miny, 0.0f);
            float inter = iw * ih;
            float iou = inter / ((parea + tb.z * tb.w - inter) + 1e-10f);
            best = fmaxf(best, iou);
        }
        float ign = (cn > 0 && best < 0.5f) ? 1.0f : 0.0f;
        float bce = bcef_(p4, m);
        float d = fabsf(m - sigmoidf_(p4));
        float focal = d * d;
        local = (m * bce + 0.5f * (1.0f - m) * ign * bce) * focal;
    }
    // block reduce: wave shfl + LDS across 4 waves
    for (int off = 32; off; off >>= 1) local += __shfl_down(local, off);
    __shared__ float wsum[4];
    int wid = threadIdx.x >> 6, lane = threadIdx.x & 63;
    if (lane == 0) wsum[wid] = local;
    __syncthreads();
    if (threadIdx.x == 0) {
        float bs = wsum[0] + wsum[1] + wsum[2] + wsum[3];
        atomicAdd(&acc[2], (double)bs);
    }
}

// xy / wh / class losses at positive cells. grid: 3*1024 blocks of 64 (1 wave).
__global__ __launch_bounds__(64) void k_pos(
        const float* __restrict__ fm0, const float* __restrict__ fm1,
        const float* __restrict__ fm2,
        const float* __restrict__ yt0, const float* __restrict__ yt1,
        const float* __restrict__ yt2,
        const float* __restrict__ anch,
        const int* __restrict__ cnt, const float* __restrict__ tgt,
        const int* __restrict__ tgtn, double* __restrict__ acc) {
    int blk = blockIdx.x;
    const float *fm, *yt;
    int G, s, anchoff;
    if (blk < 1024)      { fm = fm0; yt = yt0; G = 13; s = 0; anchoff = 6; }
    else if (blk < 2048) { blk -= 1024; fm = fm1; yt = yt1; G = 26; s = 1; anchoff = 3; }
    else                 { blk -= 2048; fm = fm2; yt = yt2; G = 52; s = 2; anchoff = 0; }
    int b = blk >> 5, slot = blk & 31;
    int cn = cnt[s * 32 + b];
    if (slot >= cn) return;
    int GG = G * G;
    float stridef = IMGF / (float)G;
    float4 tb = reinterpret_cast<const float4*>(tgt)[(s * 32 + b) * KMAX + slot];
    int n  = tgtn[(s * 32 + b) * KMAX + slot];
    int a  = n % 3;
    int sp = n / 3;
    int jj = sp % G, ii = sp / G;
    int ybase = (b * 3 * GG + n) * 85;
    int fbase = (b * 255 + a * 85) * GG + sp;
    int lane = threadIdx.x;

    // class loss: lanes 0..63 take c=lane; lanes 0..15 also take c=lane+64
    float ps = 0.0f;
    for (int c = lane; c < NCLS; c += 64) {
        float pl  = fm[fbase + (5 + c) * GG];
        float tl  = yt[ybase + 5 + c];
        float lab = 0.99f * tl + 1.25e-4f;   // (1-delta)*t + delta/NC
        ps += bcef_(pl, lab);
    }
    for (int off = 32; off; off >>= 1) ps += __shfl_down(ps, off);

    if (lane == 0) {
        float p0 = fm[fbase];
        float p1 = fm[fbase + GG];
        float p2 = fm[fbase + 2 * GG];
        float p3 = fm[fbase + 3 * GG];
        // xy
        float bcx = (sigmoidf_(p0) + (float)jj) * stridef;
        float bcy = (sigmoidf_(p1) + (float)ii) * stridef;
        float predx = bcx / stridef - (float)jj;
        float predy = bcy / stridef - (float)ii;
        float truex = tb.x / stridef - (float)jj;
        float truey = tb.y / stridef - (float)ii;
        float dx = truex - predx, dy = truey - predy;
        float bscale = 2.0f - (tb.z / IMGF) * (tb.w / IMGF);
        float xyterm = (dx * dx + dy * dy) * bscale;
        // wh
        float aw = anch[(anchoff + a) * 2], ah = anch[(anchoff + a) * 2 + 1];
        float pw = expf(p2) * (aw / stridef) * stridef;
        float ph = expf(p3) * (ah / stridef) * stridef;
        float ptw = pw / aw, pth = ph / ah;
        float ttw = tb.z / aw, tth = tb.w / ah;
        ttw = (ttw == 0.0f) ? 1.0f : ttw;
        tth = (tth == 0.0f) ? 1.0f : tth;
        ptw = (ptw == 0.0f) ? 1.0f : ptw;
        pth = (pth == 0.0f) ? 1.0f : pth;
        ttw = logf(fminf(fmaxf(ttw, 1e-9f), 1e9f));
        tth = logf(fminf(fmaxf(tth, 1e-9f), 1e9f));
        ptw = logf(fminf(fmaxf(ptw, 1e-9f), 1e9f));
        pth = logf(fminf(fmaxf(pth, 1e-9f), 1e9f));
        float dw = ttw - ptw, dh = tth - pth;
        float whterm = (dw * dw + dh * dh) * bscale;
        atomicAdd(&acc[0], (double)xyterm);
        atomicAdd(&acc[1], (double)whterm);
        atomicAdd(&acc[3], (double)ps);
    }
}

__global__ __launch_bounds__(64) void k_final(const double* __restrict__ acc,
                                              float* __restrict__ out) {
    if (threadIdx.x == 0) {
        double xy = 5.0 * acc[0] / 32.0;
        double wh = 5.0 * acc[1] / 32.0;
        double cf = acc[2] / 32.0;
        double pb = acc[3] / 32.0;
        out[0] = (float)(xy + wh + cf + pb);
        out[1] = (float)xy;
        out[2] = (float)wh;
        out[3] = (float)cf;
        out[4] = (float)pb;
    }
}

extern "C" void kernel_launch(void* const* d_in, const int* in_sizes, int n_in,
                              void* d_out, int out_size, void* d_ws, size_t ws_size,
                              hipStream_t stream) {
    const float* fm0  = (const float*)d_in[0];
    const float* yt0  = (const float*)d_in[1];
    const float* fm1  = (const float*)d_in[2];
    const float* yt1  = (const float*)d_in[3];
    const float* fm2  = (const float*)d_in[4];
    const float* yt2  = (const float*)d_in[5];
    const float* anch = (const float*)d_in[6];
    float* out = (float*)d_out;

    char* ws = (char*)d_ws;
    double* acc = (double*)ws;
    int*    cnt = (int*)(ws + OFF_CNT);
    float*  tgt = (float*)(ws + OFF_TGT);
    int*    tgtn = (int*)(ws + OFF_TGTN);
    float*  objc = nullptr;
    if (ws_size >= OFF_OBJC + (size_t)TOTAL_CELLS * sizeof(float))
        objc = (float*)(ws + OFF_OBJC);

    k_init<<<1, 128, 0, stream>>>(acc, cnt);
    k_collect<<<(TOTAL_CELLS + 255) / 256, 256, 0, stream>>>(
        yt0, yt1, yt2, cnt, tgt, tgtn, objc);
    k_conf<<<1440, 256, 0, stream>>>(
        fm0, fm1, fm2, yt0, yt1, yt2, anch, cnt, tgt, objc, acc);
    k_pos<<<3072, 64, 0, stream>>>(
        fm0, fm1, fm2, yt0, yt1, yt2, anch, cnt, tgt, tgtn, acc);
    k_final<<<1, 64, 0, stream>>>(acc, out);
}

// Round 2
// 47.568 us; speedup vs baseline: 2.5346x; 2.5346x over previous
//
#include <hip/hip_runtime.h>
#include <math.h>

// YOLO loss, 3 scales: G in {13,26,52}, B=32, A=3, 85 ch (5+80), IMG=416.
// Inputs (setup_inputs dict order): fm0, yt0, fm1, yt1, fm2, yt2, anchors(9x2)
// Output: 5 floats: total, xy, wh, conf, prob

constexpr int   NCLS  = 80;
constexpr int   KMAX  = 32;
constexpr float IMGF  = 416.0f;

// cells per scale: 32 * 3 * G*G
constexpr int C0 = 32 * 3 * 169;    // 16224
constexpr int C1 = 32 * 3 * 676;    // 64896
constexpr int C2 = 32 * 3 * 2704;   // 259584
constexpr int TOTAL_CELLS = C0 + C1 + C2; // 340704

constexpr int NCONF_BLK = 96 + 288 + 1056;   // 1440
constexpr int NPOS_BLK  = 3 * 1024;          // 3072

// ws layout (all rewritten every call; no state carried across calls):
//   [OFF_CONF)  float  conf_part[1440]
//   [OFF_POS)   float4 pos_part[3072]      (xy, wh, ps, 0)
//   [OFF_CNT)   int    cnt[96]
//   [OFF_TGT)   float4 tgt[96][32]         (x,y,w,h)
//   [OFF_TGTN)  int    tgtn[96][32]
constexpr size_t OFF_CONF = 0;
constexpr size_t OFF_POS  = OFF_CONF + NCONF_BLK * sizeof(float);       // 5760
constexpr size_t OFF_CNT  = OFF_POS + (size_t)NPOS_BLK * 16;            // 54912
constexpr size_t OFF_TGT  = OFF_CNT + 96 * sizeof(int);                 // 55296
constexpr size_t OFF_TGTN = OFF_TGT + 96 * KMAX * 4 * sizeof(float);    // 104448

__global__ __launch_bounds__(128) void k_init(int* cnt) {
    int t = threadIdx.x;
    if (t < 96) cnt[t] = 0;
}

__global__ __launch_bounds__(256) void k_collect(
        const float* __restrict__ yt0, const float* __restrict__ yt1,
        const float* __restrict__ yt2,
        int* __restrict__ cnt, float* __restrict__ tgt, int* __restrict__ tgtn) {
    int t = blockIdx.x * 256 + threadIdx.x;
    if (t >= TOTAL_CELLS) return;
    int s, local, G;
    const float* yt;
    if (t < C0)           { s = 0; local = t;           G = 13; yt = yt0; }
    else if (t < C0 + C1) { s = 1; local = t - C0;      G = 26; yt = yt1; }
    else                  { s = 2; local = t - C0 - C1; G = 52; yt = yt2; }
    int GG = G * G;
    int bn = local;                       // b*3*GG + n, with n = linear cell idx
    int b  = bn / (3 * GG);
    int n  = bn - b * 3 * GG;
    int yidx = bn * 85;
    float obj = yt[yidx + 4];
    if (obj > 0.5f) {
        int pos = atomicAdd(&cnt[s * 32 + b], 1);
        if (pos < KMAX) {
            float4 box = make_float4(yt[yidx], yt[yidx + 1], yt[yidx + 2], yt[yidx + 3]);
            reinterpret_cast<float4*>(tgt)[(s * 32 + b) * KMAX + pos] = box;
            tgtn[(s * 32 + b) * KMAX + pos] = n;
        }
    }
}

__device__ inline float sigmoidf_(float x) { return 1.0f / (1.0f + expf(-x)); }
__device__ inline float bcef_(float l, float t) {
    return fmaxf(l, 0.0f) - l * t + log1pf(expf(-fabsf(l)));
}

// conf loss over all cells. grid: 96 + 288 + 1056 = 1440 blocks of 256.
__global__ __launch_bounds__(256) void k_conf(
        const float* __restrict__ fm0, const float* __restrict__ fm1,
        const float* __restrict__ fm2,
        const float* __restrict__ anch,
        const int* __restrict__ cnt, const float* __restrict__ tgt,
        const int* __restrict__ tgtn, float* __restrict__ conf_part) {
    int blk0 = blockIdx.x;
    int blk = blk0;
    const float *fm;
    int G, chunks, s, anchoff;
    if (blk < 96)       { fm = fm0; G = 13; chunks = 1;  s = 0; anchoff = 6; }
    else if (blk < 384) { blk -= 96;  fm = fm1; G = 26; chunks = 3;  s = 1; anchoff = 3; }
    else                { blk -= 384; fm = fm2; G = 52; chunks = 11; s = 2; anchoff = 0; }
    if (s == 1) { anchoff = 3; }
    int chunk = blk % chunks;
    int ba    = blk / chunks;     // b*3 + a
    int b = ba / 3, a = ba % 3;
    int GG = G * G;
    float stridef = IMGF / (float)G;   // 32/16/8, exact powers of 2

    __shared__ float4 s_tgt[KMAX];
    __shared__ int    s_tgtn[KMAX];
    __shared__ int    s_cnt;
    if (threadIdx.x == 0) s_cnt = cnt[s * 32 + b];
    if (threadIdx.x < KMAX) {
        s_tgt[threadIdx.x]  = reinterpret_cast<const float4*>(tgt)[(s * 32 + b) * KMAX + threadIdx.x];
        s_tgtn[threadIdx.x] = tgtn[(s * 32 + b) * KMAX + threadIdx.x];
    }
    __syncthreads();

    int sp = chunk * 256 + threadIdx.x;
    float local = 0.0f;
    if (sp < GG) {
        int jj = sp % G, ii = sp / G;
        int n = sp * 3 + a;                 // reference's flattened cell index
        int fbase = (b * 255 + a * 85) * GG + sp;
        float p0 = fm[fbase];
        float p1 = fm[fbase + GG];
        float p2 = fm[fbase + 2 * GG];
        float p3 = fm[fbase + 3 * GG];
        float p4 = fm[fbase + 4 * GG];
        float aw = anch[(anchoff + a) * 2], ah = anch[(anchoff + a) * 2 + 1];
        // predicted box (replicates reference arithmetic)
        float cx = (sigmoidf_(p0) + (float)jj) * stridef;
        float cy = (sigmoidf_(p1) + (float)ii) * stridef;
        float pw = expf(p2) * (aw / stridef) * stridef;
        float ph = expf(p3) * (ah / stridef) * stridef;
        float parea = pw * ph;
        int cn = s_cnt;
        float best = 0.0f;
        float m = 0.0f;                     // obj mask reconstructed from target list
        for (int k = 0; k < cn; ++k) {
            float4 tb = s_tgt[k];
            if (s_tgtn[k] == n) m = 1.0f;
            float minx = fmaxf(cx - pw * 0.5f, tb.x - tb.z * 0.5f);
            float maxx = fminf(cx + pw * 0.5f, tb.x + tb.z * 0.5f);
            float miny = fmaxf(cy - ph * 0.5f, tb.y - tb.w * 0.5f);
            float maxy = fminf(cy + ph * 0.5f, tb.y + tb.w * 0.5f);
            float iw = fmaxf(maxx - minx, 0.0f);
            float ih = fmaxf(maxy - miny, 0.0f);
            float inter = iw * ih;
            float iou = inter / ((parea + tb.z * tb.w - inter) + 1e-10f);
            best = fmaxf(best, iou);
        }
        float ign = (cn > 0 && best < 0.5f) ? 1.0f : 0.0f;
        float bce = bcef_(p4, m);
        float d = fabsf(m - sigmoidf_(p4));
        float focal = d * d;
        local = (m * bce + 0.5f * (1.0f - m) * ign * bce) * focal;
    }
    // block reduce: wave shfl + LDS across 4 waves
    for (int off = 32; off; off >>= 1) local += __shfl_down(local, off);
    __shared__ float wsum[4];
    int wid = threadIdx.x >> 6, lane = threadIdx.x & 63;
    if (lane == 0) wsum[wid] = local;
    __syncthreads();
    if (threadIdx.x == 0)
        conf_part[blk0] = wsum[0] + wsum[1] + wsum[2] + wsum[3];
}

// xy / wh / class losses at positive cells. grid: 3*1024 blocks of 64 (1 wave).
__global__ __launch_bounds__(64) void k_pos(
        const float* __restrict__ fm0, const float* __restrict__ fm1,
        const float* __restrict__ fm2,
        const float* __restrict__ yt0, const float* __restrict__ yt1,
        const float* __restrict__ yt2,
        const float* __restrict__ anch,
        const int* __restrict__ cnt, const float* __restrict__ tgt,
        const int* __restrict__ tgtn, float4* __restrict__ pos_part) {
    int blk0 = blockIdx.x;
    int blk = blk0;
    const float *fm, *yt;
    int G, s, anchoff;
    if (blk < 1024)      { fm = fm0; yt = yt0; G = 13; s = 0; anchoff = 6; }
    else if (blk < 2048) { blk -= 1024; fm = fm1; yt = yt1; G = 26; s = 1; anchoff = 3; }
    else                 { blk -= 2048; fm = fm2; yt = yt2; G = 52; s = 2; anchoff = 0; }
    int b = blk >> 5, slot = blk & 31;
    int cn = cnt[s * 32 + b];
    int lane = threadIdx.x;
    if (slot >= cn) {
        if (lane == 0) pos_part[blk0] = make_float4(0.f, 0.f, 0.f, 0.f);
        return;
    }
    int GG = G * G;
    float stridef = IMGF / (float)G;
    float4 tb = reinterpret_cast<const float4*>(tgt)[(s * 32 + b) * KMAX + slot];
    int n  = tgtn[(s * 32 + b) * KMAX + slot];
    int a  = n % 3;
    int sp = n / 3;
    int jj = sp % G, ii = sp / G;
    int ybase = ((b * 3 * GG) + n) * 85;
    int fbase = (b * 255 + a * 85) * GG + sp;

    // class loss: lanes 0..63 take c=lane; lanes 0..15 also take c=lane+64
    float ps = 0.0f;
    for (int c = lane; c < NCLS; c += 64) {
        float pl  = fm[fbase + (5 + c) * GG];
        float tl  = yt[ybase + 5 + c];
        float lab = 0.99f * tl + 1.25e-4f;   // (1-delta)*t + delta/NC
        ps += bcef_(pl, lab);
    }
    for (int off = 32; off; off >>= 1) ps += __shfl_down(ps, off);

    if (lane == 0) {
        float p0 = fm[fbase];
        float p1 = fm[fbase + GG];
        float p2 = fm[fbase + 2 * GG];
        float p3 = fm[fbase + 3 * GG];
        // xy
        float bcx = (sigmoidf_(p0) + (float)jj) * stridef;
        float bcy = (sigmoidf_(p1) + (float)ii) * stridef;
        float predx = bcx / stridef - (float)jj;
        float predy = bcy / stridef - (float)ii;
        float truex = tb.x / stridef - (float)jj;
        float truey = tb.y / stridef - (float)ii;
        float dx = truex - predx, dy = truey - predy;
        float bscale = 2.0f - (tb.z / IMGF) * (tb.w / IMGF);
        float xyterm = (dx * dx + dy * dy) * bscale;
        // wh
        float aw = anch[(anchoff + a) * 2], ah = anch[(anchoff + a) * 2 + 1];
        float pw = expf(p2) * (aw / stridef) * stridef;
        float ph = expf(p3) * (ah / stridef) * stridef;
        float ptw = pw / aw, pth = ph / ah;
        float ttw = tb.z / aw, tth = tb.w / ah;
        ttw = (ttw == 0.0f) ? 1.0f : ttw;
        tth = (tth == 0.0f) ? 1.0f : tth;
        ptw = (ptw == 0.0f) ? 1.0f : ptw;
        pth = (pth == 0.0f) ? 1.0f : pth;
        ttw = logf(fminf(fmaxf(ttw, 1e-9f), 1e9f));
        tth = logf(fminf(fmaxf(tth, 1e-9f), 1e9f));
        ptw = logf(fminf(fmaxf(ptw, 1e-9f), 1e9f));
        pth = logf(fminf(fmaxf(pth, 1e-9f), 1e9f));
        float dw = ttw - ptw, dh = tth - pth;
        float whterm = (dw * dw + dh * dh) * bscale;
        pos_part[blk0] = make_float4(xyterm, whterm, ps, 0.0f);
    }
}

// Sum partials (double accumulation) and emit the 5 outputs.
__global__ __launch_bounds__(512) void k_reduce(
        const float* __restrict__ conf_part, const float4* __restrict__ pos_part,
        float* __restrict__ out) {
    int t = threadIdx.x;
    double c = 0.0, x = 0.0, w = 0.0, p = 0.0;
    for (int i = t; i < NCONF_BLK; i += 512) c += (double)conf_part[i];
    for (int i = t; i < NPOS_BLK; i += 512) {
        float4 v = pos_part[i];
        x += (double)v.x; w += (double)v.y; p += (double)v.z;
    }
    for (int off = 32; off; off >>= 1) {
        c += __shfl_down(c, off);
        x += __shfl_down(x, off);
        w += __shfl_down(w, off);
        p += __shfl_down(p, off);
    }
    __shared__ double sc[8], sx[8], sw[8], spp[8];
    int wid = t >> 6, lane = t & 63;
    if (lane == 0) { sc[wid] = c; sx[wid] = x; sw[wid] = w; spp[wid] = p; }
    __syncthreads();
    if (t == 0) {
        double C = 0, X = 0, W = 0, P = 0;
        for (int i = 0; i < 8; ++i) { C += sc[i]; X += sx[i]; W += sw[i]; P += spp[i]; }
        double xy = 5.0 * X / 32.0;
        double wh = 5.0 * W / 32.0;
        double cf = C / 32.0;
        double pb = P / 32.0;
        out[0] = (float)(xy + wh + cf + pb);
        out[1] = (float)xy;
        out[2] = (float)wh;
        out[3] = (float)cf;
        out[4] = (float)pb;
    }
}

extern "C" void kernel_launch(void* const* d_in, const int* in_sizes, int n_in,
                              void* d_out, int out_size, void* d_ws, size_t ws_size,
                              hipStream_t stream) {
    const float* fm0  = (const float*)d_in[0];
    const float* yt0  = (const float*)d_in[1];
    const float* fm1  = (const float*)d_in[2];
    const float* yt1  = (const float*)d_in[3];
    const float* fm2  = (const float*)d_in[4];
    const float* yt2  = (const float*)d_in[5];
    const float* anch = (const float*)d_in[6];
    float* out = (float*)d_out;

    char* ws = (char*)d_ws;
    float*  conf_part = (float*)(ws + OFF_CONF);
    float4* pos_part  = (float4*)(ws + OFF_POS);
    int*    cnt  = (int*)(ws + OFF_CNT);
    float*  tgt  = (float*)(ws + OFF_TGT);
    int*    tgtn = (int*)(ws + OFF_TGTN);

    k_init<<<1, 128, 0, stream>>>(cnt);
    k_collect<<<(TOTAL_CELLS + 255) / 256, 256, 0, stream>>>(
        yt0, yt1, yt2, cnt, tgt, tgtn);
    k_conf<<<NCONF_BLK, 256, 0, stream>>>(
        fm0, fm1, fm2, anch, cnt, tgt, tgtn, conf_part);
    k_pos<<<NPOS_BLK, 64, 0, stream>>>(
        fm0, fm1, fm2, yt0, yt1, yt2, anch, cnt, tgt, tgtn, pos_part);
    k_reduce<<<1, 512, 0, stream>>>(conf_part, pos_part, out);
}